// Round 5
// baseline (875.641 us; speedup 1.0000x reference)
//
#include <hip/hip_runtime.h>
#include <hip/hip_bf16.h>
#include <stdint.h>

typedef unsigned short u16;
typedef unsigned int   u32;
typedef __attribute__((ext_vector_type(8))) short bf16x8;
typedef __attribute__((ext_vector_type(4))) float f32x4;

#define GLAS  __attribute__((address_space(1)))
#define LDSAS __attribute__((address_space(3)))

// async global->LDS, 16B per lane. LDS dest is wave-uniform base + lane*16.
__device__ __forceinline__ void gl_lds16(const void* g, void* l) {
    __builtin_amdgcn_global_load_lds((const GLAS u32*)(uintptr_t)g,
                                     (LDSAS u32*)(u32)(uintptr_t)l, 16, 0, 0);
}

// RNE fp32->bf16
__device__ __forceinline__ u16 f2bf_rne(float f) {
    u32 u = __float_as_uint(f);
    u32 r = u + 0x7fffu + ((u >> 16) & 1u);
    return (u16)(r >> 16);
}
// packed pair (v_cvt_pk_bf16_f32 on gfx950), low16 = a
__device__ __forceinline__ u32 pk_bf2(float a, float b) {
    __hip_bfloat162 h = __float22bfloat162_rn(float2{a, b});
    u32 u; __builtin_memcpy(&u, &h, 4);
    return u;
}
__device__ __forceinline__ float bfbits_lo(u32 p) { return __uint_as_float(p << 16); }
__device__ __forceinline__ float bfbits_hi(u32 p) { return __uint_as_float(p & 0xffff0000u); }

__device__ __forceinline__ void unpack8(uint4 u, float* f) {
    f[0] = bfbits_lo(u.x); f[1] = bfbits_hi(u.x);
    f[2] = bfbits_lo(u.y); f[3] = bfbits_hi(u.y);
    f[4] = bfbits_lo(u.z); f[5] = bfbits_hi(u.z);
    f[6] = bfbits_lo(u.w); f[7] = bfbits_hi(u.w);
}

// ---------------- weight transpose + convert: WT[n][k] = bf16(W[k][n]) ----------------
struct WtArgs { const float* W[4]; u16* WT[4]; };

__global__ __launch_bounds__(256) void wtrans(WtArgs a) {
    const int z = blockIdx.z;
    const float* __restrict__ W = a.W[z];
    u16* __restrict__ WT = a.WT[z];
    __shared__ float tile[64][65];
    const int n0 = blockIdx.x * 64, k0 = blockIdx.y * 64;
    const int tid = threadIdx.x;
    const int r = tid >> 6, c = tid & 63;
    #pragma unroll
    for (int p = 0; p < 16; ++p) {
        const int row = p * 4 + r;
        tile[row][c] = W[(size_t)(k0 + row) * 1024 + n0 + c];
    }
    __syncthreads();
    #pragma unroll
    for (int p = 0; p < 16; ++p) {
        const int row = p * 4 + r;   // n index within tile
        WT[(size_t)(n0 + row) * 1024 + k0 + c] = f2bf_rne(tile[c][row]);
    }
}

// ---------------- fp32 -> bf16 streaming convert (up to 3 tensors per launch) --------
struct CvtArgs { const float* src[3]; u16* dst[3]; };

__global__ __launch_bounds__(256) void cvt3(CvtArgs a, int n8) {
    const int z = blockIdx.y;
    const float* __restrict__ src = a.src[z];
    u16* __restrict__ dst = a.dst[z];
    const int stride = gridDim.x * 256;
    for (int i = blockIdx.x * 256 + threadIdx.x; i < n8; i += stride) {
        const float4* s = (const float4*)(src + (size_t)i * 8);
        float4 x = s[0], y = s[1];
        uint4 o;
        o.x = pk_bf2(x.x, x.y); o.y = pk_bf2(x.z, x.w);
        o.z = pk_bf2(y.x, y.y); o.w = pk_bf2(y.z, y.w);
        *(uint4*)(dst + (size_t)i * 8) = o;
    }
}

// ---------------- GEMM: C[m][n] = sum_k A[m][k] * BT[n][k] + bias[n] ----------------
// m97 2-barrier structure, 128x128 tile, BK=64. XOR swizzle byte^=(row&7)<<4 applied
// as pre-swizzled SOURCE col (LDS dest linear, rule-21) + same XOR on ds_read side.
// Round-4 verified: 0 bank conflicts, 848 TF, MfmaUtil 37.4% -> at structure ceiling.
struct GemmArgs { const u16* A[3]; const u16* BT[3]; const float* bias[3]; void* C[3]; };

template<bool OUT_F32>
__global__ __launch_bounds__(256, 2)
void gemm_bt(GemmArgs ga, int M, int N, int K) {
    __shared__ u16 As[128 * 64];
    __shared__ u16 Bs[128 * 64];
    const int L = blockIdx.x;
    const int z = L >> 11;               // 2048 blocks per z
    const int r = L & 2047;
    const int xcd = r & 7;
    const int slot = r >> 3;             // 0..255 within partition
    const int m0 = (xcd * 32 + (slot >> 3)) * 128;
    const int n0 = (slot & 7) * 128;

    const u16*   __restrict__ A    = ga.A[z];
    const u16*   __restrict__ BT   = ga.BT[z];
    const float* __restrict__ bias = ga.bias[z];
    const int tid = threadIdx.x;
    const int lane = tid & 63;
    const int wave = tid >> 6;

    f32x4 acc[4][4] = {};

    const int srow = lane >> 3;                     // 0..7 within 8-row chunk
    const int scol = ((lane & 7) ^ srow) * 8;       // pre-swizzled source col (u16)

    const int wm = (wave >> 1) * 64;
    const int wn = (wave & 1) * 64;
    const int fr = lane & 15;
    const int fk = (lane >> 4) * 8;
    const int fx = (fr & 7) << 3;                   // read-side XOR (u16 units)

    for (int k0 = 0; k0 < K; k0 += 64) {
        // ---- stage A and B tiles (128x64 bf16 each) via async global->LDS
        #pragma unroll
        for (int cc = 0; cc < 4; ++cc) {
            const int chunk = cc * 4 + wave;        // 0..15, 8 rows each
            gl_lds16(A  + (size_t)(m0 + chunk * 8 + srow) * K + (k0 + scol),
                     &As[chunk * 512]);
            gl_lds16(BT + (size_t)(n0 + chunk * 8 + srow) * K + (k0 + scol),
                     &Bs[chunk * 512]);
        }
        __syncthreads();

        // ---- fragments + MFMA (2 k-subtiles of 32)
        bf16x8 af[4][2], bfr[4][2];
        #pragma unroll
        for (int i = 0; i < 4; ++i) {
            const int rowb = (wm + i * 16 + fr) * 64;
            af[i][0] = *(const bf16x8*)&As[rowb + ((0 * 32 + fk) ^ fx)];
            af[i][1] = *(const bf16x8*)&As[rowb + ((1 * 32 + fk) ^ fx)];
        }
        #pragma unroll
        for (int j = 0; j < 4; ++j) {
            const int rowb = (wn + j * 16 + fr) * 64;
            bfr[j][0] = *(const bf16x8*)&Bs[rowb + ((0 * 32 + fk) ^ fx)];
            bfr[j][1] = *(const bf16x8*)&Bs[rowb + ((1 * 32 + fk) ^ fx)];
        }
        #pragma unroll
        for (int kk = 0; kk < 2; ++kk)
            #pragma unroll
            for (int i = 0; i < 4; ++i)
                #pragma unroll
                for (int j = 0; j < 4; ++j)
                    acc[i][j] = __builtin_amdgcn_mfma_f32_16x16x32_bf16(
                        af[i][kk], bfr[j][kk], acc[i][j], 0, 0, 0);
        __syncthreads();
    }

    // ---- epilogue: C/D layout col=lane&15, row=(lane>>4)*4+rr
    const int r0 = m0 + wm + (lane >> 4) * 4;
    const int c0 = n0 + wn + (lane & 15);
    #pragma unroll
    for (int j = 0; j < 4; ++j) {
        const int col = c0 + j * 16;
        const float bv = bias[col];
        #pragma unroll
        for (int i = 0; i < 4; ++i) {
            #pragma unroll
            for (int rr = 0; rr < 4; ++rr) {
                const int row = r0 + i * 16 + rr;
                const float v = acc[i][j][rr] + bv;
                if constexpr (OUT_F32) ((float*)ga.C[z])[(size_t)row * N + col] = v;
                else                   ((u16*)ga.C[z])[(size_t)row * N + col] = f2bf_rne(v);
            }
        }
    }
    (void)M;
}

// ---------------- attention over head axis, per (b, g=l/16) tile ----------------
// Q[b,l,h,d] = QL[b, h*256+g, t*64+d], l = g*16+t   (faithful to reference reshape)
// 512 threads: h = tid&15, dh = (tid>>4)&1 (d-half), t = tid>>5.
// v3: K AND V staged together up-front (64 KB, all DMA in flight, ONE drain),
// no mid-kernel barrier; j-loops unroll 2 for multiple outstanding LDS reads.
__global__ __launch_bounds__(512, 4)
void attn(const u16* __restrict__ QL, const u16* __restrict__ KL, const u16* __restrict__ VL,
          u16* __restrict__ CTX, float* __restrict__ WOUT) {
    __shared__ u16 KVs[32 * 1024];   // [0,16K): K rows; [16K,32K): V rows (u16 units)
    const int bg = blockIdx.x;
    const int b = bg >> 8, g = bg & 255;
    const int tid = threadIdx.x, lane = tid & 63, wave = tid >> 6;
    const size_t boff = (size_t)b * (4096 * 1024);

    // ---- stage K and V (2 x 32 KB): 32 chunks of 1 KB each, 4 per wave each
    #pragma unroll
    for (int it = 0; it < 4; ++it) {
        const int c = it * 8 + wave;           // 0..31
        const int row = c >> 1, half = c & 1;
        const size_t gidx = boff + (size_t)(row * 256 + g) * 1024 + half * 512 + lane * 8;
        gl_lds16(KL + gidx, &KVs[c * 512]);
        gl_lds16(VL + gidx, &KVs[16384 + c * 512]);
    }

    const int h = tid & 15, dh = (tid >> 4) & 1, t = tid >> 5;
    const int dof = t * 64 + dh * 32;

    // ---- Q half-row into registers (overlaps the K/V DMA)
    float qf[32];
    const u16* qp = QL + boff + (size_t)(h * 256 + g) * 1024 + dof;
    #pragma unroll
    for (int c4 = 0; c4 < 4; ++c4) {
        uint4 u = *(const uint4*)(qp + c4 * 8);
        unpack8(u, &qf[c4 * 8]);
    }
    __syncthreads();   // single drain: K, V in LDS; Q in regs

    // ---- scores over heads j (partial over 32 d, completed via shfl pair)
    float w[16];
    #pragma unroll 2
    for (int j = 0; j < 16; ++j) {
        const u16* kp = &KVs[j * 1024 + dof];
        float a = 0.f;
        #pragma unroll
        for (int c4 = 0; c4 < 4; ++c4) {
            uint4 u = *(const uint4*)(kp + c4 * 8);
            float kf[8]; unpack8(u, kf);
            #pragma unroll
            for (int d = 0; d < 8; ++d) a = fmaf(qf[c4 * 8 + d], kf[d], a);
        }
        a += __shfl_xor(a, 16);
        w[j] = a * 0.125f;   // hd^-0.5 = 1/8
    }
    // ---- softmax over j (replicated in both dh lanes; identical values)
    float mx = w[0];
    #pragma unroll
    for (int j = 1; j < 16; ++j) mx = fmaxf(mx, w[j]);
    float sum = 0.f;
    #pragma unroll
    for (int j = 0; j < 16; ++j) { w[j] = __expf(w[j] - mx); sum += w[j]; }
    const float inv = 1.f / sum;
    #pragma unroll
    for (int j = 0; j < 16; ++j) w[j] *= inv;

    // ---- ctx = sum_j w[j] * V[j] (32-d half per thread); V already resident
    float cx[32];
    #pragma unroll
    for (int d = 0; d < 32; ++d) cx[d] = 0.f;
    #pragma unroll 2
    for (int j = 0; j < 16; ++j) {
        const u16* vp = &KVs[16384 + j * 1024 + dof];
        const float wj = w[j];
        #pragma unroll
        for (int c4 = 0; c4 < 4; ++c4) {
            uint4 u = *(const uint4*)(vp + c4 * 8);
            float vf[8]; unpack8(u, vf);
            #pragma unroll
            for (int d = 0; d < 8; ++d) cx[c4 * 8 + d] = fmaf(wj, vf[d], cx[c4 * 8 + d]);
        }
    }
    // ---- write ctx_merged[b, h*256+g, t*64+dh*32+d] as bf16
    u16* cp = CTX + boff + (size_t)(h * 256 + g) * 1024 + dof;
    #pragma unroll
    for (int c4 = 0; c4 < 4; ++c4) {
        uint4 o;
        o.x = pk_bf2(cx[c4 * 8 + 0], cx[c4 * 8 + 1]);
        o.y = pk_bf2(cx[c4 * 8 + 2], cx[c4 * 8 + 3]);
        o.z = pk_bf2(cx[c4 * 8 + 4], cx[c4 * 8 + 5]);
        o.w = pk_bf2(cx[c4 * 8 + 6], cx[c4 * 8 + 7]);
        *(uint4*)(cp + c4 * 8) = o;
    }
    // ---- weights[b, l, h, j] (dh==0 lanes only; w identical in both halves)
    if (dh == 0) {
        float4* wp = (float4*)(WOUT + ((size_t)((b * 4096 + g * 16 + t) * 16 + h) * 16));
        wp[0] = float4{w[0],  w[1],  w[2],  w[3]};
        wp[1] = float4{w[4],  w[5],  w[6],  w[7]};
        wp[2] = float4{w[8],  w[9],  w[10], w[11]};
        wp[3] = float4{w[12], w[13], w[14], w[15]};
    }
}

// ---------------- host ----------------
extern "C" void kernel_launch(void* const* d_in, const int* in_sizes, int n_in,
                              void* d_out, int out_size, void* d_ws, size_t ws_size,
                              hipStream_t stream) {
    const float* q  = (const float*)d_in[0];
    const float* k  = (const float*)d_in[1];
    const float* v  = (const float*)d_in[2];
    const float* Wq = (const float*)d_in[3];
    const float* bq = (const float*)d_in[4];
    const float* Wk = (const float*)d_in[5];
    const float* bk = (const float*)d_in[6];
    const float* Wv = (const float*)d_in[7];
    const float* bv = (const float*)d_in[8];
    const float* Wo = (const float*)d_in[9];
    const float* bo = (const float*)d_in[10];

    const int M = 32768, D = 1024;
    const size_t MD = (size_t)M * D;
    const int n8 = (int)(MD / 8);

    u16* WT0 = (u16*)d_ws;
    u16* WT1 = WT0 + 1048576;
    u16* WT2 = WT1 + 1048576;
    u16* WT3 = WT2 + 1048576;
    u16* big0 = WT3 + 1048576;

    float* out  = (float*)d_out;
    float* wout = out + MD;

    WtArgs wa{{Wq, Wk, Wv, Wo}, {WT0, WT1, WT2, WT3}};
    wtrans<<<dim3(16, 16, 4), 256, 0, stream>>>(wa);

    const size_t needBig = 2ull * (4ull * 1048576 + 6ull * MD);   // ~392 MiB
    if (ws_size >= needBig) {
        // fused path: 3 bf16 input copies live at once.
        // QKV GEMM split into 3 dispatches (diagnostic: unblocks top-5 profiling view).
        u16* QB = big0;      u16* KB = QB + MD;  u16* VB = KB + MD;
        u16* QL = VB + MD;   u16* KL = QL + MD;  u16* VL = KL + MD;
        u16* CTX = QB;       // QB dead after GEMM1
        CvtArgs ca{{q, k, v}, {QB, KB, VB}};
        cvt3<<<dim3(2048, 3), 256, 0, stream>>>(ca, n8);
        const u16* ab[3]   = {QB, KB, VB};
        const u16* wt[3]   = {WT0, WT1, WT2};
        const float* bb[3] = {bq, bk, bv};
        u16* dst[3]        = {QL, KL, VL};
        for (int i = 0; i < 3; ++i) {
            GemmArgs g1{{ab[i], ab[i], ab[i]}, {wt[i], wt[i], wt[i]},
                        {bb[i], bb[i], bb[i]}, {dst[i], dst[i], dst[i]}};
            gemm_bt<false><<<dim3(2048), 256, 0, stream>>>(g1, M, D, D);
        }
        attn<<<dim3(2048), 512, 0, stream>>>(QL, KL, VL, CTX, wout);
        GemmArgs g2{{CTX, CTX, CTX}, {WT3, WT3, WT3}, {bo, bo, bo}, {out, out, out}};
        gemm_bt<true><<<dim3(2048), 256, 0, stream>>>(g2, M, D, D);
    } else {
        // conservative path: one shared bf16 A-buffer (264 MiB footprint)
        u16* AB = big0;
        u16* QL = AB + MD;   u16* KL = QL + MD;  u16* VL = KL + MD;
        u16* CTX = AB;       // AB dead after the three GEMM1s
        const float* src[3]  = {q, k, v};
        const float* bia[3]  = {bq, bk, bv};
        u16* wt[3]           = {WT0, WT1, WT2};
        u16* dst[3]          = {QL, KL, VL};
        for (int i = 0; i < 3; ++i) {
            CvtArgs ca{{src[i], src[i], src[i]}, {AB, AB, AB}};
            cvt3<<<dim3(2048, 1), 256, 0, stream>>>(ca, n8);
            GemmArgs g1{{AB, AB, AB}, {wt[i], wt[i], wt[i]}, {bia[i], bia[i], bia[i]},
                        {dst[i], dst[i], dst[i]}};
            gemm_bt<false><<<dim3(2048), 256, 0, stream>>>(g1, M, D, D);
        }
        attn<<<dim3(2048), 512, 0, stream>>>(QL, KL, VL, CTX, wout);
        GemmArgs g2{{CTX, CTX, CTX}, {WT3, WT3, WT3}, {bo, bo, bo}, {out, out, out}};
        gemm_bt<true><<<dim3(2048), 256, 0, stream>>>(g2, M, D, D);
    }
}

// Round 6
// 846.560 us; speedup vs baseline: 1.0344x; 1.0344x over previous
//
#include <hip/hip_runtime.h>
#include <hip/hip_bf16.h>
#include <stdint.h>

typedef unsigned short u16;
typedef unsigned int   u32;
typedef __attribute__((ext_vector_type(8))) short bf16x8;
typedef __attribute__((ext_vector_type(4))) float f32x4;

#define GLAS  __attribute__((address_space(1)))
#define LDSAS __attribute__((address_space(3)))

// async global->LDS, 16B per lane. LDS dest is wave-uniform base + lane*16.
__device__ __forceinline__ void gl_lds16(const void* g, void* l) {
    __builtin_amdgcn_global_load_lds((const GLAS u32*)(uintptr_t)g,
                                     (LDSAS u32*)(u32)(uintptr_t)l, 16, 0, 0);
}

// RNE fp32->bf16
__device__ __forceinline__ u16 f2bf_rne(float f) {
    u32 u = __float_as_uint(f);
    u32 r = u + 0x7fffu + ((u >> 16) & 1u);
    return (u16)(r >> 16);
}
// packed pair (v_cvt_pk_bf16_f32 on gfx950), low16 = a
__device__ __forceinline__ u32 pk_bf2(float a, float b) {
    __hip_bfloat162 h = __float22bfloat162_rn(float2{a, b});
    u32 u; __builtin_memcpy(&u, &h, 4);
    return u;
}
__device__ __forceinline__ float bfbits_lo(u32 p) { return __uint_as_float(p << 16); }
__device__ __forceinline__ float bfbits_hi(u32 p) { return __uint_as_float(p & 0xffff0000u); }

__device__ __forceinline__ void unpack8(uint4 u, float* f) {
    f[0] = bfbits_lo(u.x); f[1] = bfbits_hi(u.x);
    f[2] = bfbits_lo(u.y); f[3] = bfbits_hi(u.y);
    f[4] = bfbits_lo(u.z); f[5] = bfbits_hi(u.z);
    f[6] = bfbits_lo(u.w); f[7] = bfbits_hi(u.w);
}

// ---------------- fused prep: weight transpose+convert AND fp32->bf16 activations ----
// blocks [0,1024): WT[n][k] = bf16(W[k][n]) for 4 weight matrices (64x64 tiles)
// blocks [1024, 1024+3*2048): unit-stride fp32->bf16 convert of q,k,v
//   (one float4 per thread per iter -> 16B-lane-stride loads, 8B stores; the round-5
//    cvt3 read 2 float4/thread = 32B lane stride = half-utilized transactions, 2.6 TB/s)
struct PrepArgs { const float* W[4]; u16* WT[4]; const float* src[3]; u16* dst[3]; };

__global__ __launch_bounds__(256) void prep(PrepArgs a, int n4) {
    __shared__ float tile[64][65];
    const int bx = blockIdx.x;
    const int tid = threadIdx.x;
    if (bx < 1024) {
        const int z = bx >> 8;
        const float* __restrict__ W = a.W[z];
        u16* __restrict__ WT = a.WT[z];
        const int n0 = (bx & 15) * 64, k0 = ((bx >> 4) & 15) * 64;
        const int r = tid >> 6, c = tid & 63;
        #pragma unroll
        for (int p = 0; p < 16; ++p) {
            const int row = p * 4 + r;
            tile[row][c] = W[(size_t)(k0 + row) * 1024 + n0 + c];
        }
        __syncthreads();
        #pragma unroll
        for (int p = 0; p < 16; ++p) {
            const int row = p * 4 + r;   // n index within tile
            WT[(size_t)(n0 + row) * 1024 + k0 + c] = f2bf_rne(tile[c][row]);
        }
    } else {
        const int cidx = bx - 1024;
        const int z = cidx >> 11;            // 2048 blocks per tensor
        const int cx = cidx & 2047;
        const float* __restrict__ src = a.src[z];
        u16* __restrict__ dst = a.dst[z];
        const int stride = 2048 * 256;
        for (int i = cx * 256 + tid; i < n4; i += stride) {
            float4 x = *((const float4*)src + i);
            uint2 o;
            o.x = pk_bf2(x.x, x.y);
            o.y = pk_bf2(x.z, x.w);
            *((uint2*)dst + i) = o;
        }
    }
}

// standalone unit-stride convert (conservative path only)
__global__ __launch_bounds__(256) void cvt1(const float* __restrict__ src,
                                            u16* __restrict__ dst, int n4) {
    const int stride = gridDim.x * 256;
    for (int i = blockIdx.x * 256 + (int)threadIdx.x; i < n4; i += stride) {
        float4 x = *((const float4*)src + i);
        uint2 o;
        o.x = pk_bf2(x.x, x.y);
        o.y = pk_bf2(x.z, x.w);
        *((uint2*)dst + i) = o;
    }
}

// weight transpose (conservative path only)
struct WtArgs { const float* W[4]; u16* WT[4]; };

__global__ __launch_bounds__(256) void wtrans(WtArgs a) {
    const int z = blockIdx.z;
    const float* __restrict__ W = a.W[z];
    u16* __restrict__ WT = a.WT[z];
    __shared__ float tile[64][65];
    const int n0 = blockIdx.x * 64, k0 = blockIdx.y * 64;
    const int tid = threadIdx.x;
    const int r = tid >> 6, c = tid & 63;
    #pragma unroll
    for (int p = 0; p < 16; ++p) {
        const int row = p * 4 + r;
        tile[row][c] = W[(size_t)(k0 + row) * 1024 + n0 + c];
    }
    __syncthreads();
    #pragma unroll
    for (int p = 0; p < 16; ++p) {
        const int row = p * 4 + r;
        WT[(size_t)(n0 + row) * 1024 + k0 + c] = f2bf_rne(tile[c][row]);
    }
}

// ---------------- GEMM: C[m][n] = sum_k A[m][k] * BT[n][k] + bias[n] ----------------
// m97 2-barrier structure, 128x128 tile, BK=64. XOR swizzle byte^=(row&7)<<4 applied
// as pre-swizzled SOURCE col (LDS dest linear, rule-21) + same XOR on ds_read side.
// Round-4 verified: 0 bank conflicts, 848 TF, MfmaUtil 37.4% -> at structure ceiling.
struct GemmArgs { const u16* A[3]; const u16* BT[3]; const float* bias[3]; void* C[3]; };

template<bool OUT_F32>
__global__ __launch_bounds__(256, 2)
void gemm_bt(GemmArgs ga, int M, int N, int K) {
    __shared__ u16 As[128 * 64];
    __shared__ u16 Bs[128 * 64];
    const int L = blockIdx.x;
    const int z = L >> 11;               // 2048 blocks per z
    const int r = L & 2047;
    const int xcd = r & 7;
    const int slot = r >> 3;             // 0..255 within partition
    const int m0 = (xcd * 32 + (slot >> 3)) * 128;
    const int n0 = (slot & 7) * 128;

    const u16*   __restrict__ A    = ga.A[z];
    const u16*   __restrict__ BT   = ga.BT[z];
    const float* __restrict__ bias = ga.bias[z];
    const int tid = threadIdx.x;
    const int lane = tid & 63;
    const int wave = tid >> 6;

    f32x4 acc[4][4] = {};

    const int srow = lane >> 3;                     // 0..7 within 8-row chunk
    const int scol = ((lane & 7) ^ srow) * 8;       // pre-swizzled source col (u16)

    const int wm = (wave >> 1) * 64;
    const int wn = (wave & 1) * 64;
    const int fr = lane & 15;
    const int fk = (lane >> 4) * 8;
    const int fx = (fr & 7) << 3;                   // read-side XOR (u16 units)

    for (int k0 = 0; k0 < K; k0 += 64) {
        // ---- stage A and B tiles (128x64 bf16 each) via async global->LDS
        #pragma unroll
        for (int cc = 0; cc < 4; ++cc) {
            const int chunk = cc * 4 + wave;        // 0..15, 8 rows each
            gl_lds16(A  + (size_t)(m0 + chunk * 8 + srow) * K + (k0 + scol),
                     &As[chunk * 512]);
            gl_lds16(BT + (size_t)(n0 + chunk * 8 + srow) * K + (k0 + scol),
                     &Bs[chunk * 512]);
        }
        __syncthreads();

        // ---- fragments + MFMA (2 k-subtiles of 32)
        bf16x8 af[4][2], bfr[4][2];
        #pragma unroll
        for (int i = 0; i < 4; ++i) {
            const int rowb = (wm + i * 16 + fr) * 64;
            af[i][0] = *(const bf16x8*)&As[rowb + ((0 * 32 + fk) ^ fx)];
            af[i][1] = *(const bf16x8*)&As[rowb + ((1 * 32 + fk) ^ fx)];
        }
        #pragma unroll
        for (int j = 0; j < 4; ++j) {
            const int rowb = (wn + j * 16 + fr) * 64;
            bfr[j][0] = *(const bf16x8*)&Bs[rowb + ((0 * 32 + fk) ^ fx)];
            bfr[j][1] = *(const bf16x8*)&Bs[rowb + ((1 * 32 + fk) ^ fx)];
        }
        #pragma unroll
        for (int kk = 0; kk < 2; ++kk)
            #pragma unroll
            for (int i = 0; i < 4; ++i)
                #pragma unroll
                for (int j = 0; j < 4; ++j)
                    acc[i][j] = __builtin_amdgcn_mfma_f32_16x16x32_bf16(
                        af[i][kk], bfr[j][kk], acc[i][j], 0, 0, 0);
        __syncthreads();
    }

    // ---- epilogue: C/D layout col=lane&15, row=(lane>>4)*4+rr
    const int r0 = m0 + wm + (lane >> 4) * 4;
    const int c0 = n0 + wn + (lane & 15);
    #pragma unroll
    for (int j = 0; j < 4; ++j) {
        const int col = c0 + j * 16;
        const float bv = bias[col];
        #pragma unroll
        for (int i = 0; i < 4; ++i) {
            #pragma unroll
            for (int rr = 0; rr < 4; ++rr) {
                const int row = r0 + i * 16 + rr;
                const float v = acc[i][j][rr] + bv;
                if constexpr (OUT_F32) ((float*)ga.C[z])[(size_t)row * N + col] = v;
                else                   ((u16*)ga.C[z])[(size_t)row * N + col] = f2bf_rne(v);
            }
        }
    }
    (void)M;
}

// ---------------- attention over head axis, per (b, g=l/16) tile ----------------
// Q[b,l,h,d] = QL[b, h*256+g, t*64+d], l = g*16+t   (faithful to reference reshape)
// 512 threads: h = tid&15, dh = (tid>>4)&1 (d-half), t = tid>>5.
// K AND V staged together up-front (64 KB, all DMA in flight, ONE drain).
__global__ __launch_bounds__(512, 4)
void attn(const u16* __restrict__ QL, const u16* __restrict__ KL, const u16* __restrict__ VL,
          u16* __restrict__ CTX, float* __restrict__ WOUT) {
    __shared__ u16 KVs[32 * 1024];   // [0,16K): K rows; [16K,32K): V rows (u16 units)
    const int bg = blockIdx.x;
    const int b = bg >> 8, g = bg & 255;
    const int tid = threadIdx.x, lane = tid & 63, wave = tid >> 6;
    const size_t boff = (size_t)b * (4096 * 1024);

    // ---- stage K and V (2 x 32 KB): 32 chunks of 1 KB each, 4 per wave each
    #pragma unroll
    for (int it = 0; it < 4; ++it) {
        const int c = it * 8 + wave;           // 0..31
        const int row = c >> 1, half = c & 1;
        const size_t gidx = boff + (size_t)(row * 256 + g) * 1024 + half * 512 + lane * 8;
        gl_lds16(KL + gidx, &KVs[c * 512]);
        gl_lds16(VL + gidx, &KVs[16384 + c * 512]);
    }

    const int h = tid & 15, dh = (tid >> 4) & 1, t = tid >> 5;
    const int dof = t * 64 + dh * 32;

    // ---- Q half-row into registers (overlaps the K/V DMA)
    float qf[32];
    const u16* qp = QL + boff + (size_t)(h * 256 + g) * 1024 + dof;
    #pragma unroll
    for (int c4 = 0; c4 < 4; ++c4) {
        uint4 u = *(const uint4*)(qp + c4 * 8);
        unpack8(u, &qf[c4 * 8]);
    }
    __syncthreads();   // single drain: K, V in LDS; Q in regs

    // ---- scores over heads j (partial over 32 d, completed via shfl pair)
    float w[16];
    #pragma unroll 2
    for (int j = 0; j < 16; ++j) {
        const u16* kp = &KVs[j * 1024 + dof];
        float a = 0.f;
        #pragma unroll
        for (int c4 = 0; c4 < 4; ++c4) {
            uint4 u = *(const uint4*)(kp + c4 * 8);
            float kf[8]; unpack8(u, kf);
            #pragma unroll
            for (int d = 0; d < 8; ++d) a = fmaf(qf[c4 * 8 + d], kf[d], a);
        }
        a += __shfl_xor(a, 16);
        w[j] = a * 0.125f;   // hd^-0.5 = 1/8
    }
    // ---- softmax over j (replicated in both dh lanes; identical values)
    float mx = w[0];
    #pragma unroll
    for (int j = 1; j < 16; ++j) mx = fmaxf(mx, w[j]);
    float sum = 0.f;
    #pragma unroll
    for (int j = 0; j < 16; ++j) { w[j] = __expf(w[j] - mx); sum += w[j]; }
    const float inv = 1.f / sum;
    #pragma unroll
    for (int j = 0; j < 16; ++j) w[j] *= inv;

    // ---- ctx = sum_j w[j] * V[j] (32-d half per thread); V already resident
    float cx[32];
    #pragma unroll
    for (int d = 0; d < 32; ++d) cx[d] = 0.f;
    #pragma unroll 2
    for (int j = 0; j < 16; ++j) {
        const u16* vp = &KVs[16384 + j * 1024 + dof];
        const float wj = w[j];
        #pragma unroll
        for (int c4 = 0; c4 < 4; ++c4) {
            uint4 u = *(const uint4*)(vp + c4 * 8);
            float vf[8]; unpack8(u, vf);
            #pragma unroll
            for (int d = 0; d < 8; ++d) cx[c4 * 8 + d] = fmaf(wj, vf[d], cx[c4 * 8 + d]);
        }
    }
    // ---- write ctx_merged[b, h*256+g, t*64+dh*32+d] as bf16
    u16* cp = CTX + boff + (size_t)(h * 256 + g) * 1024 + dof;
    #pragma unroll
    for (int c4 = 0; c4 < 4; ++c4) {
        uint4 o;
        o.x = pk_bf2(cx[c4 * 8 + 0], cx[c4 * 8 + 1]);
        o.y = pk_bf2(cx[c4 * 8 + 2], cx[c4 * 8 + 3]);
        o.z = pk_bf2(cx[c4 * 8 + 4], cx[c4 * 8 + 5]);
        o.w = pk_bf2(cx[c4 * 8 + 6], cx[c4 * 8 + 7]);
        *(uint4*)(cp + c4 * 8) = o;
    }
    // ---- weights[b, l, h, j] (dh==0 lanes only; w identical in both halves)
    if (dh == 0) {
        float4* wp = (float4*)(WOUT + ((size_t)((b * 4096 + g * 16 + t) * 16 + h) * 16));
        wp[0] = float4{w[0],  w[1],  w[2],  w[3]};
        wp[1] = float4{w[4],  w[5],  w[6],  w[7]};
        wp[2] = float4{w[8],  w[9],  w[10], w[11]};
        wp[3] = float4{w[12], w[13], w[14], w[15]};
    }
}

// ---------------- host ----------------
extern "C" void kernel_launch(void* const* d_in, const int* in_sizes, int n_in,
                              void* d_out, int out_size, void* d_ws, size_t ws_size,
                              hipStream_t stream) {
    const float* q  = (const float*)d_in[0];
    const float* k  = (const float*)d_in[1];
    const float* v  = (const float*)d_in[2];
    const float* Wq = (const float*)d_in[3];
    const float* bq = (const float*)d_in[4];
    const float* Wk = (const float*)d_in[5];
    const float* bk = (const float*)d_in[6];
    const float* Wv = (const float*)d_in[7];
    const float* bv = (const float*)d_in[8];
    const float* Wo = (const float*)d_in[9];
    const float* bo = (const float*)d_in[10];

    const int M = 32768, D = 1024;
    const size_t MD = (size_t)M * D;
    const int n4 = (int)(MD / 4);

    u16* WT0 = (u16*)d_ws;
    u16* WT1 = WT0 + 1048576;
    u16* WT2 = WT1 + 1048576;
    u16* WT3 = WT2 + 1048576;
    u16* big0 = WT3 + 1048576;

    float* out  = (float*)d_out;
    float* wout = out + MD;

    const size_t needBig = 2ull * (4ull * 1048576 + 6ull * MD);   // ~392 MiB
    if (ws_size >= needBig) {
        // fused path, 4 dispatches total: prep -> QKV gemm -> attn -> out gemm
        u16* QB = big0;      u16* KB = QB + MD;  u16* VB = KB + MD;
        u16* QL = VB + MD;   u16* KL = QL + MD;  u16* VL = KL + MD;
        u16* CTX = QB;       // QB dead after GEMM1
        PrepArgs pa{{Wq, Wk, Wv, Wo}, {WT0, WT1, WT2, WT3}, {q, k, v}, {QB, KB, VB}};
        prep<<<dim3(1024 + 3 * 2048), 256, 0, stream>>>(pa, n4);
        GemmArgs g1{{QB, KB, VB}, {WT0, WT1, WT2}, {bq, bk, bv}, {QL, KL, VL}};
        gemm_bt<false><<<dim3(3 * 2048), 256, 0, stream>>>(g1, M, D, D);
        attn<<<dim3(2048), 512, 0, stream>>>(QL, KL, VL, CTX, wout);
        GemmArgs g2{{CTX, CTX, CTX}, {WT3, WT3, WT3}, {bo, bo, bo}, {out, out, out}};
        gemm_bt<true><<<dim3(2048), 256, 0, stream>>>(g2, M, D, D);
    } else {
        // conservative path: one shared bf16 A-buffer (264 MiB footprint)
        u16* AB = big0;
        u16* QL = AB + MD;   u16* KL = QL + MD;  u16* VL = KL + MD;
        u16* CTX = AB;       // AB dead after the three GEMM1s
        WtArgs wa{{Wq, Wk, Wv, Wo}, {WT0, WT1, WT2, WT3}};
        wtrans<<<dim3(16, 16, 4), 256, 0, stream>>>(wa);
        const float* src[3]  = {q, k, v};
        const float* bia[3]  = {bq, bk, bv};
        u16* wt[3]           = {WT0, WT1, WT2};
        u16* dst[3]          = {QL, KL, VL};
        for (int i = 0; i < 3; ++i) {
            cvt1<<<dim3(2048), 256, 0, stream>>>(src[i], AB, n4);
            GemmArgs g1{{AB, AB, AB}, {wt[i], wt[i], wt[i]}, {bia[i], bia[i], bia[i]},
                        {dst[i], dst[i], dst[i]}};
            gemm_bt<false><<<dim3(2048), 256, 0, stream>>>(g1, M, D, D);
        }
        attn<<<dim3(2048), 512, 0, stream>>>(QL, KL, VL, CTX, wout);
        GemmArgs g2{{CTX, CTX, CTX}, {WT3, WT3, WT3}, {bo, bo, bo}, {out, out, out}};
        gemm_bt<true><<<dim3(2048), 256, 0, stream>>>(g2, M, D, D);
    }
}